// Round 2
// baseline (2430.775 us; speedup 1.0000x reference)
//
#include <hip/hip_runtime.h>

#define NNODES 800000
#define KT 27
#define EPSV 1e-5f

typedef _Float16 half8 __attribute__((ext_vector_type(8)));
typedef _Float16 half4 __attribute__((ext_vector_type(4)));
typedef float    f32x4 __attribute__((ext_vector_type(4)));
typedef unsigned int u32x2 __attribute__((ext_vector_type(2)));

#define MFMA(A,B,C) __builtin_amdgcn_mfma_f32_16x16x32_f16((A),(B),(C),0,0,0)

// CK-style barrier: drain LDS ops only, leave global loads (vmcnt) in flight.
__device__ __forceinline__ void bar_lgkm() {
  asm volatile("s_waitcnt lgkmcnt(0)\n\ts_barrier" ::: "memory");
}

// ---------------------------------------------------------------------------
// Truncated-f16 residual codec. Byte = sign | exp4 | man3 of the f16 of l,
// valid because |l| <= |x|*2^-11 < 2 => f16 exp field <= 8 < 16. Decode is
// the exact inverse bit-expansion (subnormals included).
// ---------------------------------------------------------------------------
__device__ __forceinline__ unsigned enc_lo(float x, _Float16 h) {
  const float l = x - (float)h;
  union { _Float16 f; unsigned short u; } cv;
  cv.f = (_Float16)l;
  const unsigned b = cv.u;
  return (((b & 0x7fffu) + 0x40u) >> 7) | ((b >> 8) & 0x80u);
}

__device__ __forceinline__ unsigned dec2(unsigned v) {
  // two bytes (bits 0-7, 8-15) -> two packed f16
  return ((v & 0x7fu) << 7) | ((v & 0x80u) << 8) |
         ((v & 0x7f00u) << 15) | ((v & 0x8000u) << 16);
}

__device__ __forceinline__ half8 dec8(u32x2 p) {
  union { unsigned u[4]; half8 h; } r;
  r.u[0] = dec2(p.x & 0xffffu);
  r.u[1] = dec2(p.x >> 16);
  r.u[2] = dec2(p.y & 0xffffu);
  r.u[3] = dec2(p.y >> 16);
  return r.h;
}

// ---------------------------------------------------------------------------
// GroupNorm over one lane-local group of 4 channels.
// ---------------------------------------------------------------------------
__device__ __forceinline__ f32x4 gn4(f32x4 v, const float* __restrict__ w,
                                     const float* __restrict__ b, int cb) {
  const float mu = (v[0] + v[1] + v[2] + v[3]) * 0.25f;
  f32x4 d;
#pragma unroll
  for (int j = 0; j < 4; ++j) d[j] = v[j] - mu;
  const float var = (d[0] * d[0] + d[1] * d[1] + d[2] * d[2] + d[3] * d[3]) * 0.25f;
  const float rs = 1.0f / sqrtf(var + EPSV);
  const f32x4 wv = *(const f32x4*)(w + cb);
  const f32x4 bv = *(const f32x4*)(b + cb);
  f32x4 r;
#pragma unroll
  for (int j = 0; j < 4; ++j) r[j] = d[j] * rs * wv[j] + bv[j];
  return r;
}

// ---------------------------------------------------------------------------
// Prepass 1: split f32 -> f16 hi + byte lo.
// ---------------------------------------------------------------------------
__global__ __launch_bounds__(256) void k_split(const float* __restrict__ x,
                                               _Float16* __restrict__ hi,
                                               unsigned* __restrict__ lo8, int n4) {
  const int i = blockIdx.x * 256 + threadIdx.x;
  if (i >= n4) return;
  const f32x4 v = ((const f32x4*)x)[i];
  half4 h;
  unsigned pb = 0;
#pragma unroll
  for (int j = 0; j < 4; ++j) {
    h[j] = (_Float16)v[j];
    pb |= enc_lo(v[j], h[j]) << (8 * j);
  }
  ((half4*)hi)[i] = h;
  lo8[i] = pb;
}

// ---------------------------------------------------------------------------
// Prepass 2: pre-swizzle weights into MFMA A-operand LDS-image layout
// (f16 hi plane + f16 lo plane; weights cost no gather bandwidth).
// waT: [27][t:4][h:2][lane:64][8]   wbT: [27][t:4][kc:2][h:2][lane:64][8]
// ---------------------------------------------------------------------------
__global__ __launch_bounds__(256) void k_prepw(const float* __restrict__ Wa,
                                               const float* __restrict__ Wb,
                                               const float* __restrict__ W1,
                                               _Float16* __restrict__ waT,
                                               _Float16* __restrict__ wbT,
                                               _Float16* __restrict__ w1T) {
  const int u = blockIdx.x * 256 + threadIdx.x;
  const float* s;
  _Float16* d;
  size_t db;
  int cin0, cout, cinw;
  if (u < 6912) {
    const int tap = u >> 8, r = u & 255, t = r >> 6, l = r & 63;
    cin0 = (l >> 4) * 8;
    cout = t * 16 + (l & 15);
    s = Wa + (size_t)tap * 32 * 64;
    cinw = 64;
    d = waT;
    db = ((size_t)(tap * 8 + t * 2) * 64 + l) * 8;
  } else if (u < 20736) {
    const int u2 = u - 6912;
    const int tap = u2 >> 9, r = u2 & 511, t = r >> 7, r2 = r & 127;
    const int kc = r2 >> 6, l = r2 & 63;
    cin0 = kc * 32 + (l >> 4) * 8;
    cout = t * 16 + (l & 15);
    s = Wb + (size_t)tap * 64 * 64;
    cinw = 64;
    d = wbT;
    db = ((size_t)(tap * 16 + t * 4 + kc * 2) * 64 + l) * 8;
  } else if (u < 20992) {
    const int u3 = u - 20736, t = u3 >> 6, l = u3 & 63;
    cin0 = (l >> 4) * 8;
    cout = t * 16 + (l & 15);
    s = W1;
    cinw = 64;
    d = w1T;
    db = ((size_t)(t * 2) * 64 + l) * 8;
  } else {
    return;
  }
  half8 h, l8;
#pragma unroll
  for (int j = 0; j < 8; ++j) {
    const float v = s[(size_t)(cin0 + j) * cinw + cout];
    h[j] = (_Float16)v;
    l8[j] = (_Float16)(v - (float)h[j]);
  }
  *(half8*)(d + db) = h;
  *(half8*)(d + db + 512) = l8;
}

// ---------------------------------------------------------------------------
// Kernel A: h = relu(GN(octree_conv(data, neigh, Wa))) -> f16 hi + byte lo
// 1-tap LDS chunks, gathers software-pipelined one tap ahead across barriers.
// ---------------------------------------------------------------------------
__global__ __launch_bounds__(256, 4) void k_conva(
    const _Float16* __restrict__ dhi, const unsigned char* __restrict__ dlo8,
    const int* __restrict__ neigh, const _Float16* __restrict__ waT,
    const float* __restrict__ gw, const float* __restrict__ gb,
    _Float16* __restrict__ hhi, unsigned char* __restrict__ hlo8) {
  __shared__ _Float16 s_w[4096];  // one tap: 8 KB
  const int tid = threadIdx.x;
  const int wave = tid >> 6, lane = tid & 63;
  const int cl = lane & 15, q = lane >> 4;
  const int node0 = blockIdx.x * 128;
  const int r0 = node0 + wave * 32 + cl;
  const int* nrow0 = neigh + (size_t)r0 * KT;
  const int* nrow1 = neigh + (size_t)(r0 + 16) * KT;

  f32x4 acc[4][2] = {};

  // prologue: indices for taps 0,1; operands for tap 0
  int ci0 = nrow0[0], ci1 = nrow1[0];
  int ni0 = nrow0[1], ni1 = nrow1[1];
  half8 cxh0 = *(const half8*)(dhi + (size_t)ci0 * 32 + q * 8);
  u32x2 cp0 = *(const u32x2*)(dlo8 + (size_t)ci0 * 32 + q * 8);
  half8 cxh1 = *(const half8*)(dhi + (size_t)ci1 * 32 + q * 8);
  u32x2 cp1 = *(const u32x2*)(dlo8 + (size_t)ci1 * 32 + q * 8);

  for (int c = 0; c < KT; ++c) {
    bar_lgkm();
    // stage loads first (oldest in vmcnt FIFO)
    const f32x4* src = (const f32x4*)(waT + (size_t)c * 4096);
    const f32x4 w0 = src[tid];
    const f32x4 w1 = src[tid + 256];
    // then next-tap gathers (stay in flight across ds_write wait + barrier)
    const int pi0 = (c < KT - 1) ? ni0 : 0;
    const int pi1 = (c < KT - 1) ? ni1 : 0;
    const half8 nxh0 = *(const half8*)(dhi + (size_t)pi0 * 32 + q * 8);
    const u32x2 np0 = *(const u32x2*)(dlo8 + (size_t)pi0 * 32 + q * 8);
    const half8 nxh1 = *(const half8*)(dhi + (size_t)pi1 * 32 + q * 8);
    const u32x2 np1 = *(const u32x2*)(dlo8 + (size_t)pi1 * 32 + q * 8);
    const int t2 = (c + 2 < KT) ? (c + 2) : (KT - 1);
    const int ti0 = nrow0[t2];
    const int ti1 = nrow1[t2];
    f32x4* dst = (f32x4*)s_w;
    dst[tid] = w0;
    dst[tid + 256] = w1;
    bar_lgkm();

    const half8 cxl0 = dec8(cp0);
    const half8 cxl1 = dec8(cp1);
#pragma unroll
    for (int t = 0; t < 4; ++t) {
      const half8 wh = *(const half8*)(s_w + ((t * 2 + 0) * 64 + lane) * 8);
      const half8 wl = *(const half8*)(s_w + ((t * 2 + 1) * 64 + lane) * 8);
      acc[t][0] = MFMA(wh, cxh0, acc[t][0]);
      acc[t][0] = MFMA(wh, cxl0, acc[t][0]);
      acc[t][0] = MFMA(wl, cxh0, acc[t][0]);
      acc[t][1] = MFMA(wh, cxh1, acc[t][1]);
      acc[t][1] = MFMA(wh, cxl1, acc[t][1]);
      acc[t][1] = MFMA(wl, cxh1, acc[t][1]);
    }
    cxh0 = nxh0; cxh1 = nxh1; cp0 = np0; cp1 = np1;
    ni0 = ti0; ni1 = ti1;
  }

#pragma unroll
  for (int t = 0; t < 4; ++t)
#pragma unroll
    for (int nt = 0; nt < 2; ++nt) {
      const int node = node0 + wave * 32 + nt * 16 + cl;
      const int cb = t * 16 + q * 4;
      const f32x4 g = gn4(acc[t][nt], gw, gb, cb);
      half4 h;
      unsigned pb = 0;
#pragma unroll
      for (int j = 0; j < 4; ++j) {
        const float v = fmaxf(g[j], 0.0f);
        h[j] = (_Float16)v;
        pb |= enc_lo(v, h[j]) << (8 * j);
      }
      *(half4*)(hhi + (size_t)node * 64 + cb) = h;
      *(unsigned*)(hlo8 + (size_t)node * 64 + cb) = pb;
    }
}

// ---------------------------------------------------------------------------
// Kernel B: out = relu(GN(octree_conv(h, neigh, Wb)) + GN(data @ W1)) -> f32
// ---------------------------------------------------------------------------
__global__ __launch_bounds__(256, 4) void k_convb(
    const _Float16* __restrict__ hhi, const unsigned char* __restrict__ hlo8,
    const _Float16* __restrict__ dhi, const unsigned char* __restrict__ dlo8,
    const int* __restrict__ neigh, const _Float16* __restrict__ wbT,
    const _Float16* __restrict__ w1T,
    const float* __restrict__ gbw, const float* __restrict__ gbb,
    const float* __restrict__ gsw, const float* __restrict__ gsb,
    float* __restrict__ out) {
  __shared__ _Float16 s_w[8192];  // one tap: 16 KB
  const int tid = threadIdx.x;
  const int wave = tid >> 6, lane = tid & 63;
  const int cl = lane & 15, q = lane >> 4;
  const int node0 = blockIdx.x * 128;
  const int r0 = node0 + wave * 32 + cl;
  const int* nrow0 = neigh + (size_t)r0 * KT;
  const int* nrow1 = neigh + (size_t)(r0 + 16) * KT;

  f32x4 acc[4][2] = {};

  int ci0 = nrow0[0], ci1 = nrow1[0];
  int ni0 = nrow0[1], ni1 = nrow1[1];
  half8 ca0 = *(const half8*)(hhi + (size_t)ci0 * 64 + q * 8);
  half8 cb0 = *(const half8*)(hhi + (size_t)ci0 * 64 + 32 + q * 8);
  u32x2 cpa0 = *(const u32x2*)(hlo8 + (size_t)ci0 * 64 + q * 8);
  u32x2 cpb0 = *(const u32x2*)(hlo8 + (size_t)ci0 * 64 + 32 + q * 8);
  half8 ca1 = *(const half8*)(hhi + (size_t)ci1 * 64 + q * 8);
  half8 cb1 = *(const half8*)(hhi + (size_t)ci1 * 64 + 32 + q * 8);
  u32x2 cpa1 = *(const u32x2*)(hlo8 + (size_t)ci1 * 64 + q * 8);
  u32x2 cpb1 = *(const u32x2*)(hlo8 + (size_t)ci1 * 64 + 32 + q * 8);

  for (int c = 0; c < KT; ++c) {
    bar_lgkm();
    const f32x4* src = (const f32x4*)(wbT + (size_t)c * 8192);
    const f32x4 w0 = src[tid];
    const f32x4 w1 = src[tid + 256];
    const f32x4 w2 = src[tid + 512];
    const f32x4 w3 = src[tid + 768];
    const int pi0 = (c < KT - 1) ? ni0 : 0;
    const int pi1 = (c < KT - 1) ? ni1 : 0;
    const half8 na0 = *(const half8*)(hhi + (size_t)pi0 * 64 + q * 8);
    const half8 nb0 = *(const half8*)(hhi + (size_t)pi0 * 64 + 32 + q * 8);
    const u32x2 npa0 = *(const u32x2*)(hlo8 + (size_t)pi0 * 64 + q * 8);
    const u32x2 npb0 = *(const u32x2*)(hlo8 + (size_t)pi0 * 64 + 32 + q * 8);
    const half8 na1 = *(const half8*)(hhi + (size_t)pi1 * 64 + q * 8);
    const half8 nb1 = *(const half8*)(hhi + (size_t)pi1 * 64 + 32 + q * 8);
    const u32x2 npa1 = *(const u32x2*)(hlo8 + (size_t)pi1 * 64 + q * 8);
    const u32x2 npb1 = *(const u32x2*)(hlo8 + (size_t)pi1 * 64 + 32 + q * 8);
    const int t2 = (c + 2 < KT) ? (c + 2) : (KT - 1);
    const int ti0 = nrow0[t2];
    const int ti1 = nrow1[t2];
    f32x4* dst = (f32x4*)s_w;
    dst[tid] = w0;
    dst[tid + 256] = w1;
    dst[tid + 512] = w2;
    dst[tid + 768] = w3;
    bar_lgkm();

    const half8 cla0 = dec8(cpa0);
    const half8 clb0 = dec8(cpb0);
    const half8 cla1 = dec8(cpa1);
    const half8 clb1 = dec8(cpb1);
#pragma unroll
    for (int t = 0; t < 4; ++t) {
      const int wb = (t * 4) * 512;
      const half8 wha = *(const half8*)(s_w + wb + lane * 8);
      const half8 wla = *(const half8*)(s_w + wb + 512 + lane * 8);
      const half8 whb = *(const half8*)(s_w + wb + 1024 + lane * 8);
      const half8 wlb = *(const half8*)(s_w + wb + 1536 + lane * 8);
      acc[t][0] = MFMA(wha, ca0, acc[t][0]);
      acc[t][0] = MFMA(wha, cla0, acc[t][0]);
      acc[t][0] = MFMA(wla, ca0, acc[t][0]);
      acc[t][0] = MFMA(whb, cb0, acc[t][0]);
      acc[t][0] = MFMA(whb, clb0, acc[t][0]);
      acc[t][0] = MFMA(wlb, cb0, acc[t][0]);
      acc[t][1] = MFMA(wha, ca1, acc[t][1]);
      acc[t][1] = MFMA(wha, cla1, acc[t][1]);
      acc[t][1] = MFMA(wla, ca1, acc[t][1]);
      acc[t][1] = MFMA(whb, cb1, acc[t][1]);
      acc[t][1] = MFMA(whb, clb1, acc[t][1]);
      acc[t][1] = MFMA(wlb, cb1, acc[t][1]);
    }
    ca0 = na0; cb0 = nb0; cpa0 = npa0; cpb0 = npb0;
    ca1 = na1; cb1 = nb1; cpa1 = npa1; cpb1 = npb1;
    ni0 = ti0; ni1 = ti1;
  }

  // Shortcut: sc = data @ W1 (own node, linear access).
  f32x4 sc[4][2] = {};
  {
    const int n0g = node0 + wave * 32 + cl;
    const half8 sh0 = *(const half8*)(dhi + (size_t)n0g * 32 + q * 8);
    const u32x2 sp0 = *(const u32x2*)(dlo8 + (size_t)n0g * 32 + q * 8);
    const half8 sh1 = *(const half8*)(dhi + (size_t)(n0g + 16) * 32 + q * 8);
    const u32x2 sp1 = *(const u32x2*)(dlo8 + (size_t)(n0g + 16) * 32 + q * 8);
    const half8 sl0 = dec8(sp0);
    const half8 sl1 = dec8(sp1);
#pragma unroll
    for (int t = 0; t < 4; ++t) {
      const half8 wh = *(const half8*)(w1T + ((size_t)(t * 2) * 64 + lane) * 8);
      const half8 wl = *(const half8*)(w1T + ((size_t)(t * 2 + 1) * 64 + lane) * 8);
      sc[t][0] = MFMA(wh, sh0, sc[t][0]);
      sc[t][0] = MFMA(wh, sl0, sc[t][0]);
      sc[t][0] = MFMA(wl, sh0, sc[t][0]);
      sc[t][1] = MFMA(wh, sh1, sc[t][1]);
      sc[t][1] = MFMA(wh, sl1, sc[t][1]);
      sc[t][1] = MFMA(wl, sh1, sc[t][1]);
    }
  }

#pragma unroll
  for (int t = 0; t < 4; ++t)
#pragma unroll
    for (int nt = 0; nt < 2; ++nt) {
      const int node = node0 + wave * 32 + nt * 16 + cl;
      const int cb = t * 16 + q * 4;
      const f32x4 a = gn4(acc[t][nt], gbw, gbb, cb);
      const f32x4 s = gn4(sc[t][nt], gsw, gsb, cb);
      f32x4 o;
#pragma unroll
      for (int j = 0; j < 4; ++j) o[j] = fmaxf(a[j] + s[j], 0.0f);
      *(f32x4*)(out + (size_t)node * 64 + cb) = o;
    }
}

// ---------------------------------------------------------------------------
extern "C" void kernel_launch(void* const* d_in, const int* in_sizes, int n_in,
                              void* d_out, int out_size, void* d_ws, size_t ws_size,
                              hipStream_t stream) {
  const float* data = (const float*)d_in[0];
  const int* neigh = (const int*)d_in[1];
  const float* Wa = (const float*)d_in[2];
  const float* gaw = (const float*)d_in[3];
  const float* gab = (const float*)d_in[4];
  const float* Wb = (const float*)d_in[5];
  const float* gbw = (const float*)d_in[6];
  const float* gbb = (const float*)d_in[7];
  const float* W1 = (const float*)d_in[8];
  const float* gsw = (const float*)d_in[9];
  const float* gsb = (const float*)d_in[10];
  float* out = (float*)d_out;

  char* ws = (char*)d_ws;
  _Float16* dhi = (_Float16*)(ws);                        //  51,200,000 B
  unsigned char* dlo8 = (unsigned char*)(ws + 51200000);  //  25,600,000 B
  _Float16* hhi = (_Float16*)(ws + 76800000);             // 102,400,000 B
  unsigned char* hlo8 = (unsigned char*)(ws + 179200000); //  51,200,000 B
  _Float16* waT = (_Float16*)(ws + 230400000);            //     221,184 B
  _Float16* wbT = (_Float16*)(ws + 230621184);            //     442,368 B
  _Float16* w1T = (_Float16*)(ws + 231063552);            //       8,192 B

  k_split<<<25000, 256, 0, stream>>>(data, dhi, (unsigned*)dlo8, NNODES * 32 / 4);
  k_prepw<<<82, 256, 0, stream>>>(Wa, Wb, W1, waT, wbT, w1T);
  k_conva<<<NNODES / 128, 256, 0, stream>>>(dhi, dlo8, neigh, waT, gaw, gab, hhi, hlo8);
  k_convb<<<NNODES / 128, 256, 0, stream>>>(hhi, hlo8, dhi, dlo8, neigh, wbT, w1T,
                                            gbw, gbb, gsw, gsb, out);
}